// Round 4
// baseline (200.773 us; speedup 1.0000x reference)
//
#include <hip/hip_runtime.h>
#include <cstdint>
#include <math.h>

#define B_ROWS 4096
#define HALF_B 2048
#define NT_COLS 8192
#define P_POS 8
#define K_NEG 1016
#define N_PAD 3079.0f          // B - (1+K)
#define A_C 1.57694f
#define BB_C 0.89506f
#define INV_T 6.66666666667f
#define THREADS 512
#define EPT (NT_COLS / THREADS)   // 16
#define LN2_F 0.69314718056f
#define INV_LN2_F 1.44269504089f
#define NHIST 8
// g = -ln(-ln u) = GUM_C - ln2 * log2(-log2(u));  GUM_C = -ln2*log2(ln2)
#define GUM_C 0.3665129206f

// hw transcendental wrappers (avoid glibc name collisions)
__device__ __forceinline__ float hw_log2(float x) { return __builtin_amdgcn_logf(x); }
__device__ __forceinline__ float hw_exp2(float x) { return __builtin_amdgcn_exp2f(x); }
__device__ __forceinline__ float hw_ln(float x) { return hw_log2(x) * LN2_F; }

// ---- Threefry-2x32, 20 rounds, exactly JAX's schedule ----
__host__ __device__ __forceinline__ void tf2x32(uint32_t k0, uint32_t k1,
                                                uint32_t& x0, uint32_t& x1) {
  const uint32_t ks2 = k0 ^ k1 ^ 0x1BD11BDAu;
  x0 += k0; x1 += k1;
#define TF_RND(r) { x0 += x1; x1 = (x1 << (r)) | (x1 >> (32 - (r))); x1 ^= x0; }
  TF_RND(13) TF_RND(15) TF_RND(26) TF_RND(6)
  x0 += k1;  x1 += ks2 + 1u;
  TF_RND(17) TF_RND(29) TF_RND(16) TF_RND(24)
  x0 += ks2; x1 += k0 + 2u;
  TF_RND(13) TF_RND(15) TF_RND(26) TF_RND(6)
  x0 += k0;  x1 += k1 + 3u;
  TF_RND(17) TF_RND(29) TF_RND(16) TF_RND(24)
  x0 += k1;  x1 += ks2 + 4u;
  TF_RND(13) TF_RND(15) TF_RND(26) TF_RND(6)
  x0 += ks2; x1 += k0 + 5u;
#undef TF_RND
}

__device__ __forceinline__ float sim_fast(float x0, float x1, float xsq,
                                          float tx, float ty) {
  float tsq = tx * tx + ty * ty;
  float d2 = fmaxf(xsq + tsq - 2.0f * (x0 * tx + x1 * ty), 1e-12f);
  return 1.0f / (1.0f + A_C * hw_exp2(BB_C * hw_log2(d2)));
}

// bits -> gumbel score key contribution
__device__ __forceinline__ uint32_t make_key(uint32_t bits, float lw) {
  float f = __uint_as_float((bits >> 9) | 0x3f800000u) - 1.0f;
  float u = fmaxf(f, 1e-20f);
  float g = GUM_C - LN2_F * hw_log2(-hw_log2(u));
  uint32_t sb = __float_as_uint(lw + g);
  return sb ^ (0x80000000u | (uint32_t)(-(int32_t)(sb >> 31)));
}

__global__ void prelog_kernel(const float* __restrict__ wf,
                              float* __restrict__ logw) {
  int i = blockIdx.x * 256 + threadIdx.x;
  if (i < NT_COLS) logw[i] = 0.75f * logf(wf[i]);
}

__global__ __launch_bounds__(THREADS, 4) void cdr_pair_kernel(
    const float* __restrict__ x_emb, const float* __restrict__ t_emb,
    const float* __restrict__ logw, const float* __restrict__ wf,
    const int* __restrict__ pos_idx,
    float* __restrict__ row_loss, float* __restrict__ out_atomic,
    uint32_t fk0, uint32_t fk1) {
  __shared__ uint32_t skey[2][NT_COLS];   // 64 KB
  __shared__ uint32_t hist[NHIST][257];   // 8.2 KB, per-wave copies, bank-padded
  __shared__ uint32_t ssum[256];
  __shared__ uint32_t sh_scal[4];         // 0: prefix, 1: remaining, 2: tie ctr
  __shared__ int sh_pos[2][P_POS];
  __shared__ float sh_part[8];

  const int r0 = blockIdx.x;              // 0..2047
  const int r1 = r0 + HALF_B;
  const int tid = threadIdx.x;

  if (tid < P_POS) sh_pos[0][tid] = pos_idx[r0 * P_POS + tid];
  else if (tid < 2 * P_POS) sh_pos[1][tid - P_POS] = pos_idx[r1 * P_POS + (tid - P_POS)];

  const float a00 = x_emb[r0 * 2 + 0], a01 = x_emb[r0 * 2 + 1];
  const float a10 = x_emb[r1 * 2 + 0], a11 = x_emb[r1 * 2 + 1];
  const float q0 = a00 * a00 + a01 * a01;
  const float q1 = a10 * a10 + a11 * a11;

  // ---- phase 1: one threefry call feeds BOTH rows r0 and r0+2048 ----
  const uint32_t H = 16777216u;   // (B*NT)/2
#pragma unroll 1
  for (int i = 0; i < EPT; ++i) {
    const int col = i * THREADS + tid;
    const uint32_t n = (uint32_t)(r0 * NT_COLS + col);
    uint32_t xa = n, xb = n + H;
    tf2x32(fk0, fk1, xa, xb);
    const float lw = logw ? logw[col] : 0.75f * hw_ln(wf[col]);
    skey[0][col] = make_key(xa, lw);
    skey[1][col] = make_key(xb, lw);
  }
  __syncthreads();
  // scatter-zero the positive entries (replaces 8 compares per element)
  if (tid < P_POS) skey[0][sh_pos[0][tid]] = 0u;
  else if (tid < 2 * P_POS) skey[1][sh_pos[1][tid - P_POS]] = 0u;
  __syncthreads();

  for (int rs = 0; rs < 2; ++rs) {
    const uint32_t* sk = skey[rs];

    // ---- phase 2: radix-select the K-th largest key (4 x 8-bit passes) ----
    uint32_t prefix = 0u, pmask = 0u, remaining = K_NEG;
    for (int shift = 24; shift >= 0; shift -= 8) {
      for (int z = tid; z < NHIST * 257; z += THREADS) ((uint32_t*)hist)[z] = 0u;
      __syncthreads();
      uint32_t* myh = hist[tid >> 6];
#pragma unroll 1
      for (int i = 0; i < EPT; ++i) {
        const uint32_t key = sk[i * THREADS + tid];
        if ((key & pmask) == prefix) atomicAdd(&myh[(key >> shift) & 0xFFu], 1u);
      }
      __syncthreads();
      if (tid < 256) {
        uint32_t s = 0;
#pragma unroll
        for (int h = 0; h < NHIST; ++h) s += hist[h][tid];
        ssum[tid] = s;
      }
      __syncthreads();
      // suffix scan: ssum[b] = count of keys with bucket >= b
      for (int off = 1; off < 256; off <<= 1) {
        uint32_t v = 0;
        if (tid < 256) { v = ssum[tid]; if (tid + off < 256) v += ssum[tid + off]; }
        __syncthreads();
        if (tid < 256) ssum[tid] = v;
        __syncthreads();
      }
      if (tid < 256) {
        uint32_t ge = ssum[tid];
        uint32_t gt = (tid == 255) ? 0u : ssum[tid + 1];
        if (ge >= remaining && gt < remaining) {
          sh_scal[0] = prefix | ((uint32_t)tid << shift);
          sh_scal[1] = remaining - gt;
        }
      }
      __syncthreads();
      prefix = sh_scal[0];
      remaining = sh_scal[1];
      pmask |= (0xFFu << shift);
    }
    const uint32_t theta = prefix;
    const uint32_t need_ties = remaining;
    if (tid == 0) sh_scal[2] = 0u;
    __syncthreads();

    const float xa = rs ? a10 : a00;
    const float xb = rs ? a11 : a01;
    const float xq = rs ? q1 : q0;

    // ---- phase 3: sum exp(sim/T) over selected negatives ----
    float acc = 0.0f;
#pragma unroll 1
    for (int i = 0; i < EPT; ++i) {
      const int col = i * THREADS + tid;
      const uint32_t key = sk[col];
      bool inc = key > theta;
      if (key == theta) inc = (atomicAdd(&sh_scal[2], 1u) < need_ties);
      if (inc) {
        float tx = t_emb[col * 2 + 0];
        float ty = t_emb[col * 2 + 1];
        float s = sim_fast(xa, xb, xq, tx, ty);
        acc += hw_exp2(s * (INV_T * INV_LN2_F));
      }
    }
#pragma unroll
    for (int off = 32; off > 0; off >>= 1) acc += __shfl_down(acc, off);
    if ((tid & 63) == 0) sh_part[tid >> 6] = acc;
    __syncthreads();

    if (tid == 0) {
      float s = 0.0f;
#pragma unroll
      for (int w = 0; w < 8; ++w) s += sh_part[w];
      float psum = 0.0f;
      for (int p = 0; p < P_POS; ++p) {
        int c = sh_pos[rs][p];
        psum += sim_fast(xa, xb, xq, t_emb[c * 2 + 0], t_emb[c * 2 + 1]);
      }
      float pos = psum * (1.0f / P_POS);
      float zpos = pos * INV_T;
      float S = s + hw_exp2(zpos * INV_LN2_F) + N_PAD;
      float loss = logf(S) - zpos;
      int r = rs ? r1 : r0;
      if (row_loss) row_loss[r] = loss;
      else atomicAdd(out_atomic, loss * (1.0f / B_ROWS));
    }
    __syncthreads();
  }
}

__global__ __launch_bounds__(256) void cdr_reduce_kernel(
    const float* __restrict__ row_loss, float* __restrict__ out) {
  __shared__ float part[4];
  float s = 0.0f;
  for (int i = threadIdx.x; i < B_ROWS; i += 256) s += row_loss[i];
#pragma unroll
  for (int off = 32; off > 0; off >>= 1) s += __shfl_down(s, off);
  if ((threadIdx.x & 63) == 0) part[threadIdx.x >> 6] = s;
  __syncthreads();
  if (threadIdx.x == 0)
    out[0] = (part[0] + part[1] + part[2] + part[3]) * (1.0f / B_ROWS);
}

__global__ void cdr_zero_kernel(float* __restrict__ out) { out[0] = 0.0f; }

extern "C" void kernel_launch(void* const* d_in, const int* in_sizes, int n_in,
                              void* d_out, int out_size, void* d_ws, size_t ws_size,
                              hipStream_t stream) {
  const float* x_emb = (const float*)d_in[0];
  const float* t_emb = (const float*)d_in[1];
  const float* wf    = (const float*)d_in[2];
  const int*   pidx  = (const int*)d_in[3];
  float* out = (float*)d_out;

  // folded key: fold_in(key(0), 1) = threefry2x32((0,0), (0,1))
  uint32_t fk0 = 0u, fk1 = 1u;
  tf2x32(0u, 0u, fk0, fk1);

  const bool has_logw = (ws_size >= (size_t)(NT_COLS + B_ROWS) * sizeof(float));
  const bool has_rl   = (ws_size >= (size_t)B_ROWS * sizeof(float));

  float* logw = nullptr;
  float* row_loss = nullptr;
  if (has_logw) { logw = (float*)d_ws; row_loss = (float*)d_ws + NT_COLS; }
  else if (has_rl) { row_loss = (float*)d_ws; }

  if (has_logw) {
    hipLaunchKernelGGL(prelog_kernel, dim3(NT_COLS / 256), dim3(256), 0, stream,
                       wf, logw);
  }
  if (!row_loss) {
    hipLaunchKernelGGL(cdr_zero_kernel, dim3(1), dim3(1), 0, stream, out);
  }
  hipLaunchKernelGGL(cdr_pair_kernel, dim3(HALF_B), dim3(THREADS), 0, stream,
                     x_emb, t_emb, logw, wf, pidx, row_loss, out, fk0, fk1);
  if (row_loss) {
    hipLaunchKernelGGL(cdr_reduce_kernel, dim3(1), dim3(256), 0, stream,
                       row_loss, out);
  }
}

// Round 5
// 133.184 us; speedup vs baseline: 1.5075x; 1.5075x over previous
//
#include <hip/hip_runtime.h>
#include <cstdint>
#include <math.h>

#define B_ROWS 4096
#define HALF_B 2048
#define NT_COLS 8192
#define P_POS 8
#define K_NEG 1016
#define N_PAD 3079.0f          // B - (1+K)
#define A_C 1.57694f
#define BB_C 0.89506f
#define INV_T 6.66666666667f
#define THREADS 1024
#define EPT 8                  // NT_COLS / THREADS
#define LN2_F 0.69314718056f
#define INV_LN2_F 1.44269504089f
#define NBINS 2048
// g = -ln(-ln u) = GUM_C - ln2 * log2(-log2(u));  GUM_C = -ln2*log2(ln2)
#define GUM_C 0.3665129206f

// hw transcendental wrappers (avoid glibc name collisions)
__device__ __forceinline__ float hw_log2(float x) { return __builtin_amdgcn_logf(x); }
__device__ __forceinline__ float hw_exp2(float x) { return __builtin_amdgcn_exp2f(x); }
__device__ __forceinline__ float hw_ln(float x) { return hw_log2(x) * LN2_F; }

// ---- Threefry-2x32, 20 rounds, exactly JAX's schedule ----
__host__ __device__ __forceinline__ void tf2x32(uint32_t k0, uint32_t k1,
                                                uint32_t& x0, uint32_t& x1) {
  const uint32_t ks2 = k0 ^ k1 ^ 0x1BD11BDAu;
  x0 += k0; x1 += k1;
#define TF_RND(r) { x0 += x1; x1 = (x1 << (r)) | (x1 >> (32 - (r))); x1 ^= x0; }
  TF_RND(13) TF_RND(15) TF_RND(26) TF_RND(6)
  x0 += k1;  x1 += ks2 + 1u;
  TF_RND(17) TF_RND(29) TF_RND(16) TF_RND(24)
  x0 += ks2; x1 += k0 + 2u;
  TF_RND(13) TF_RND(15) TF_RND(26) TF_RND(6)
  x0 += k0;  x1 += k1 + 3u;
  TF_RND(17) TF_RND(29) TF_RND(16) TF_RND(24)
  x0 += k1;  x1 += ks2 + 4u;
  TF_RND(13) TF_RND(15) TF_RND(26) TF_RND(6)
  x0 += ks2; x1 += k0 + 5u;
#undef TF_RND
}

__device__ __forceinline__ float sim_fast(float x0, float x1, float xsq,
                                          float tx, float ty) {
  float tsq = tx * tx + ty * ty;
  float d2 = fmaxf(xsq + tsq - 2.0f * (x0 * tx + x1 * ty), 1e-12f);
  return 1.0f / (1.0f + A_C * hw_exp2(BB_C * hw_log2(d2)));
}

// bits -> order-preserving gumbel-score key
__device__ __forceinline__ uint32_t make_key(uint32_t bits, float lw) {
  float f = __uint_as_float((bits >> 9) | 0x3f800000u) - 1.0f;
  float u = fmaxf(f, 1e-20f);
  float g = GUM_C - LN2_F * hw_log2(-hw_log2(u));
  uint32_t sb = __float_as_uint(lw + g);
  return sb ^ (0x80000000u | (uint32_t)(-(int32_t)(sb >> 31)));
}

__global__ void prelog_kernel(const float* __restrict__ wf,
                              float* __restrict__ logw) {
  int i = blockIdx.x * 256 + threadIdx.x;
  if (i < NT_COLS) logw[i] = 0.75f * logf(wf[i]);
}

__global__ __launch_bounds__(THREADS, 8) void cdr_pair_kernel(
    const float* __restrict__ x_emb, const float* __restrict__ t_emb,
    const float* __restrict__ logw, const float* __restrict__ wf,
    const int* __restrict__ pos_idx,
    float* __restrict__ row_loss, float* __restrict__ out_atomic,
    uint32_t fk0, uint32_t fk1) {
  __shared__ uint32_t hist[NBINS];      // 8 KB
  __shared__ uint32_t wsum[16];
  __shared__ uint32_t sh_scal[4];       // 0: prefix, 1: remaining, 2: tie ctr
  __shared__ int sh_pos[2 * P_POS];
  __shared__ float sh_part[16];

  const int r0 = blockIdx.x;            // 0..2047
  const int r1 = r0 + HALF_B;
  const int tid = threadIdx.x;
  const int lane = tid & 63;
  const int wv = tid >> 6;

  if (tid < P_POS) sh_pos[tid] = pos_idx[r0 * P_POS + tid];
  else if (tid < 2 * P_POS) sh_pos[tid] = pos_idx[r1 * P_POS + (tid - P_POS)];
  __syncthreads();

  // per-thread bitmask of which of my 8 slots are positives (per row)
  uint32_t m0 = 0u, m1 = 0u;
#pragma unroll
  for (int p = 0; p < P_POS; ++p) {
    int c0 = sh_pos[p], c1 = sh_pos[P_POS + p];
    if ((c0 & (THREADS - 1)) == tid) m0 |= 1u << (c0 >> 10);
    if ((c1 & (THREADS - 1)) == tid) m1 |= 1u << (c1 >> 10);
  }

  // ---- phase 1: one threefry call feeds BOTH rows; keys stay in VGPRs ----
  uint32_t k0[EPT], k1[EPT];
  const uint32_t H = 16777216u;   // (B*NT)/2
#pragma unroll
  for (int i = 0; i < EPT; ++i) {
    const int col = i * THREADS + tid;
    const uint32_t n = (uint32_t)(r0 * NT_COLS + col);
    uint32_t xa = n, xb = n + H;
    tf2x32(fk0, fk1, xa, xb);
    const float lw = logw ? logw[col] : 0.75f * hw_ln(wf[col]);
    uint32_t ka = make_key(xa, lw);
    uint32_t kb = make_key(xb, lw);
    k0[i] = ((m0 >> i) & 1u) ? 0u : ka;
    k1[i] = ((m1 >> i) & 1u) ? 0u : kb;
  }

  for (int rs = 0; rs < 2; ++rs) {
    // ---- phase 2: radix-select K-th largest (3 passes: 11/11/10 bits) ----
    uint32_t prefix = 0u, pmask = 0u, remaining = K_NEG;
#pragma unroll 1
    for (int ps = 0; ps < 3; ++ps) {
      const int shift = (ps == 0) ? 21 : (ps == 1) ? 10 : 0;
      hist[tid] = 0u;
      hist[tid + 1024] = 0u;
      __syncthreads();
#pragma unroll
      for (int i = 0; i < EPT; ++i) {
        uint32_t key = rs ? k1[i] : k0[i];
        if ((key & pmask) == prefix)
          atomicAdd(&hist[(key >> shift) & 0x7FFu], 1u);
      }
      __syncthreads();
      uint32_t h0 = hist[2 * tid], h1 = hist[2 * tid + 1];
      uint32_t P = h0 + h1;
      uint32_t incl = P;
#pragma unroll
      for (int off = 1; off < 64; off <<= 1) {
        uint32_t u = __shfl_down(incl, off);
        if (lane + off < 64) incl += u;
      }
      if (lane == 0) wsum[wv] = incl;      // whole-wave total
      __syncthreads();
      uint32_t ws = 0u;
      for (int w = wv + 1; w < 16; ++w) ws += wsum[w];
      uint32_t S = ws + (incl - P);        // sum over threads strictly after me
      uint32_t ge1 = h1 + S, gt1 = S;
      uint32_t ge0 = P + S,  gt0 = ge1;
      if (ge0 >= remaining && gt0 < remaining) {
        sh_scal[0] = prefix | ((uint32_t)(2 * tid) << shift);
        sh_scal[1] = remaining - gt0;
      }
      if (ge1 >= remaining && gt1 < remaining) {
        sh_scal[0] = prefix | ((uint32_t)(2 * tid + 1) << shift);
        sh_scal[1] = remaining - gt1;
      }
      __syncthreads();
      prefix = sh_scal[0];
      remaining = sh_scal[1];
      pmask |= (0x7FFu << shift);
    }
    const uint32_t theta = prefix;
    const uint32_t need_ties = remaining;
    if (tid == 0) sh_scal[2] = 0u;
    __syncthreads();

    // ---- phase 3: sum exp(sim/T) over selected negatives ----
    const int r = rs ? r1 : r0;
    const float xa_ = x_emb[r * 2 + 0];
    const float xb_ = x_emb[r * 2 + 1];
    const float xq = xa_ * xa_ + xb_ * xb_;
    float acc = 0.0f;
#pragma unroll
    for (int i = 0; i < EPT; ++i) {
      uint32_t key = rs ? k1[i] : k0[i];
      bool inc = key > theta;
      if (key == theta) inc = (atomicAdd(&sh_scal[2], 1u) < need_ties);
      if (inc) {
        const int col = i * THREADS + tid;
        float tx = t_emb[col * 2 + 0];
        float ty = t_emb[col * 2 + 1];
        float s = sim_fast(xa_, xb_, xq, tx, ty);
        acc += hw_exp2(s * (INV_T * INV_LN2_F));
      }
    }
#pragma unroll
    for (int off = 32; off > 0; off >>= 1) acc += __shfl_down(acc, off);
    if (lane == 0) sh_part[wv] = acc;
    __syncthreads();

    if (tid == 0) {
      float s = 0.0f;
#pragma unroll
      for (int w = 0; w < 16; ++w) s += sh_part[w];
      float psum = 0.0f;
      for (int p = 0; p < P_POS; ++p) {
        int c = sh_pos[rs * P_POS + p];
        psum += sim_fast(xa_, xb_, xq, t_emb[c * 2 + 0], t_emb[c * 2 + 1]);
      }
      float pos = psum * (1.0f / P_POS);
      float zpos = pos * INV_T;
      float S = s + hw_exp2(zpos * INV_LN2_F) + N_PAD;
      float loss = logf(S) - zpos;
      if (row_loss) row_loss[r] = loss;
      else atomicAdd(out_atomic, loss * (1.0f / B_ROWS));
    }
    __syncthreads();
  }
}

__global__ __launch_bounds__(256) void cdr_reduce_kernel(
    const float* __restrict__ row_loss, float* __restrict__ out) {
  __shared__ float part[4];
  float s = 0.0f;
  for (int i = threadIdx.x; i < B_ROWS; i += 256) s += row_loss[i];
#pragma unroll
  for (int off = 32; off > 0; off >>= 1) s += __shfl_down(s, off);
  if ((threadIdx.x & 63) == 0) part[threadIdx.x >> 6] = s;
  __syncthreads();
  if (threadIdx.x == 0)
    out[0] = (part[0] + part[1] + part[2] + part[3]) * (1.0f / B_ROWS);
}

__global__ void cdr_zero_kernel(float* __restrict__ out) { out[0] = 0.0f; }

extern "C" void kernel_launch(void* const* d_in, const int* in_sizes, int n_in,
                              void* d_out, int out_size, void* d_ws, size_t ws_size,
                              hipStream_t stream) {
  const float* x_emb = (const float*)d_in[0];
  const float* t_emb = (const float*)d_in[1];
  const float* wf    = (const float*)d_in[2];
  const int*   pidx  = (const int*)d_in[3];
  float* out = (float*)d_out;

  // folded key: fold_in(key(0), 1) = threefry2x32((0,0), (0,1))
  uint32_t fk0 = 0u, fk1 = 1u;
  tf2x32(0u, 0u, fk0, fk1);

  const bool has_logw = (ws_size >= (size_t)(NT_COLS + B_ROWS) * sizeof(float));
  const bool has_rl   = (ws_size >= (size_t)B_ROWS * sizeof(float));

  float* logw = nullptr;
  float* row_loss = nullptr;
  if (has_logw) { logw = (float*)d_ws; row_loss = (float*)d_ws + NT_COLS; }
  else if (has_rl) { row_loss = (float*)d_ws; }

  if (has_logw) {
    hipLaunchKernelGGL(prelog_kernel, dim3(NT_COLS / 256), dim3(256), 0, stream,
                       wf, logw);
  }
  if (!row_loss) {
    hipLaunchKernelGGL(cdr_zero_kernel, dim3(1), dim3(1), 0, stream, out);
  }
  hipLaunchKernelGGL(cdr_pair_kernel, dim3(HALF_B), dim3(THREADS), 0, stream,
                     x_emb, t_emb, logw, wf, pidx, row_loss, out, fk0, fk1);
  if (row_loss) {
    hipLaunchKernelGGL(cdr_reduce_kernel, dim3(1), dim3(256), 0, stream,
                       row_loss, out);
  }
}

// Round 6
// 117.107 us; speedup vs baseline: 1.7144x; 1.1373x over previous
//
#include <hip/hip_runtime.h>
#include <cstdint>
#include <math.h>

#define B_ROWS 4096
#define HALF_B 2048
#define NT_COLS 8192
#define P_POS 8
#define K_NEG 1016
#define N_PAD 3079.0f          // B - (1+K)
#define A_C 1.57694f
#define BB_C 0.89506f
#define INV_T 6.66666666667f
#define THREADS 1024
#define EPT 8                  // NT_COLS / THREADS
#define LN2_F 0.69314718056f
#define INV_LN2_F 1.44269504089f
#define NBINS 2048
#define CMAX 128
// g = -ln(-ln u) = GUM_C - ln2 * log2(-log2(u));  GUM_C = -ln2*log2(ln2)
#define GUM_C 0.3665129206f

// hw transcendental wrappers (avoid glibc name collisions)
__device__ __forceinline__ float hw_log2(float x) { return __builtin_amdgcn_logf(x); }
__device__ __forceinline__ float hw_exp2(float x) { return __builtin_amdgcn_exp2f(x); }
__device__ __forceinline__ float hw_ln(float x) { return hw_log2(x) * LN2_F; }

// ---- Threefry-2x32, 20 rounds, exactly JAX's schedule ----
__host__ __device__ __forceinline__ void tf2x32(uint32_t k0, uint32_t k1,
                                                uint32_t& x0, uint32_t& x1) {
  const uint32_t ks2 = k0 ^ k1 ^ 0x1BD11BDAu;
  x0 += k0; x1 += k1;
#define TF_RND(r) { x0 += x1; x1 = (x1 << (r)) | (x1 >> (32 - (r))); x1 ^= x0; }
  TF_RND(13) TF_RND(15) TF_RND(26) TF_RND(6)
  x0 += k1;  x1 += ks2 + 1u;
  TF_RND(17) TF_RND(29) TF_RND(16) TF_RND(24)
  x0 += ks2; x1 += k0 + 2u;
  TF_RND(13) TF_RND(15) TF_RND(26) TF_RND(6)
  x0 += k0;  x1 += k1 + 3u;
  TF_RND(17) TF_RND(29) TF_RND(16) TF_RND(24)
  x0 += k1;  x1 += ks2 + 4u;
  TF_RND(13) TF_RND(15) TF_RND(26) TF_RND(6)
  x0 += ks2; x1 += k0 + 5u;
#undef TF_RND
}

__device__ __forceinline__ float sim_fast(float x0, float x1, float xsq,
                                          float tx, float ty) {
  float tsq = tx * tx + ty * ty;
  float d2 = fmaxf(xsq + tsq - 2.0f * (x0 * tx + x1 * ty), 1e-12f);
  return 1.0f / (1.0f + A_C * hw_exp2(BB_C * hw_log2(d2)));
}

// bits -> order-preserving gumbel-score key
__device__ __forceinline__ uint32_t make_key(uint32_t bits, float lw) {
  float f = __uint_as_float((bits >> 9) | 0x3f800000u) - 1.0f;
  float u = fmaxf(f, 1e-20f);
  float g = GUM_C - LN2_F * hw_log2(-hw_log2(u));
  uint32_t sb = __float_as_uint(lw + g);
  return sb ^ (0x80000000u | (uint32_t)(-(int32_t)(sb >> 31)));
}

__global__ void prelog_kernel(const float* __restrict__ wf,
                              float* __restrict__ logw) {
  int i = blockIdx.x * 256 + threadIdx.x;
  if (i < NT_COLS) logw[i] = 0.75f * logf(wf[i]);
}

__global__ __launch_bounds__(THREADS, 8) void cdr_pair_kernel(
    const float* __restrict__ x_emb, const float* __restrict__ t_emb,
    const float* __restrict__ logw, const float* __restrict__ wf,
    const int* __restrict__ pos_idx,
    float* __restrict__ row_loss, float* __restrict__ out_atomic,
    uint32_t fk0, uint32_t fk1) {
  __shared__ uint32_t hist[2][NBINS];   // 16 KB
  __shared__ uint32_t sel[2048];        // 8 KB (exactly 2032 used)
  __shared__ uint32_t cand[2][CMAX];    // 1 KB
  __shared__ uint32_t wsumA[16], wsumB[16];
  __shared__ uint32_t sh_scal[4];       // prefA, remA, prefB, remB
  __shared__ uint32_t sh_cnt[2], sh_tie[2], sh_nsel;
  __shared__ uint32_t sh_theta[2], sh_need[2];
  __shared__ int sh_pos[2 * P_POS];
  __shared__ float shA[16], shB[16], sh_pp[16];

  const int r0 = blockIdx.x;            // 0..2047
  const int r1 = r0 + HALF_B;
  const int tid = threadIdx.x;
  const int lane = tid & 63;
  const int wv = tid >> 6;

  if (tid < P_POS) sh_pos[tid] = pos_idx[r0 * P_POS + tid];
  else if (tid < 2 * P_POS) sh_pos[tid] = pos_idx[r1 * P_POS + (tid - P_POS)];
  if (tid == 0) sh_nsel = 0u;
  if (tid < 2) { sh_cnt[tid] = 0u; sh_tie[tid] = 0u; }
  __syncthreads();

  // per-thread bitmask of which of my 8 slots are positives (per row)
  uint32_t m0 = 0u, m1 = 0u;
#pragma unroll
  for (int p = 0; p < P_POS; ++p) {
    int c0 = sh_pos[p], c1 = sh_pos[P_POS + p];
    if ((c0 & (THREADS - 1)) == tid) m0 |= 1u << (c0 >> 10);
    if ((c1 & (THREADS - 1)) == tid) m1 |= 1u << (c1 >> 10);
  }

  // ---- phase 1: one threefry call feeds BOTH rows; keys stay in VGPRs ----
  uint32_t k0[EPT], k1[EPT];
  const uint32_t H = 16777216u;   // (B*NT)/2
#pragma unroll
  for (int i = 0; i < EPT; ++i) {
    const int col = i * THREADS + tid;
    const uint32_t n = (uint32_t)(r0 * NT_COLS + col);
    uint32_t xa = n, xb = n + H;
    tf2x32(fk0, fk1, xa, xb);
    const float lw = logw ? logw[col] : 0.75f * hw_ln(wf[col]);
    uint32_t ka = make_key(xa, lw);
    uint32_t kb = make_key(xb, lw);
    k0[i] = ((m0 >> i) & 1u) ? 0u : ka;
    k1[i] = ((m1 >> i) & 1u) ? 0u : kb;
  }

  // ---- phase 2: two 11-bit radix passes, BOTH rows in parallel ----
  uint32_t prefA = 0u, prefB = 0u, remA = K_NEG, remB = K_NEG, pmask = 0u;
#pragma unroll 1
  for (int ps = 0; ps < 2; ++ps) {
    const int shift = ps ? 10 : 21;
    hist[0][tid] = 0u; hist[0][tid + 1024] = 0u;
    hist[1][tid] = 0u; hist[1][tid + 1024] = 0u;
    __syncthreads();
#pragma unroll
    for (int i = 0; i < EPT; ++i) {
      uint32_t ka = k0[i];
      if ((ka & pmask) == prefA) atomicAdd(&hist[0][(ka >> shift) & 0x7FFu], 1u);
      uint32_t kb = k1[i];
      if ((kb & pmask) == prefB) atomicAdd(&hist[1][(kb >> shift) & 0x7FFu], 1u);
    }
    __syncthreads();
    uint32_t a0 = hist[0][2 * tid], a1 = hist[0][2 * tid + 1];
    uint32_t b0 = hist[1][2 * tid], b1 = hist[1][2 * tid + 1];
    uint32_t Pa = a0 + a1, Pb = b0 + b1;
    uint32_t ia = Pa, ib = Pb;
#pragma unroll
    for (int off = 1; off < 64; off <<= 1) {
      uint32_t ua = __shfl_down(ia, off), ub = __shfl_down(ib, off);
      if (lane + off < 64) { ia += ua; ib += ub; }
    }
    if (lane == 0) { wsumA[wv] = ia; wsumB[wv] = ib; }
    __syncthreads();
    uint32_t wsA = 0u, wsB = 0u;
    for (int w = wv + 1; w < 16; ++w) { wsA += wsumA[w]; wsB += wsumB[w]; }
    uint32_t Sa = wsA + (ia - Pa);   // keys in bins strictly above my pair
    uint32_t Sb = wsB + (ib - Pb);
    {
      uint32_t gt1 = Sa, ge1 = a1 + Sa, gt0 = a1 + Sa, ge0 = Pa + Sa;
      if (ge0 >= remA && gt0 < remA) { sh_scal[0] = prefA | ((uint32_t)(2 * tid) << shift); sh_scal[1] = remA - gt0; }
      if (ge1 >= remA && gt1 < remA) { sh_scal[0] = prefA | ((uint32_t)(2 * tid + 1) << shift); sh_scal[1] = remA - gt1; }
    }
    {
      uint32_t gt1 = Sb, ge1 = b1 + Sb, gt0 = b1 + Sb, ge0 = Pb + Sb;
      if (ge0 >= remB && gt0 < remB) { sh_scal[2] = prefB | ((uint32_t)(2 * tid) << shift); sh_scal[3] = remB - gt0; }
      if (ge1 >= remB && gt1 < remB) { sh_scal[2] = prefB | ((uint32_t)(2 * tid + 1) << shift); sh_scal[3] = remB - gt1; }
    }
    __syncthreads();
    prefA = sh_scal[0]; remA = sh_scal[1];
    prefB = sh_scal[2]; remB = sh_scal[3];
    pmask |= (0x7FFu << shift);
  }

  // ---- phase 2b: collect candidates sharing the 22-bit prefix; resolve exactly ----
#pragma unroll
  for (int i = 0; i < EPT; ++i) {
    uint32_t ka = k0[i];
    if ((ka & pmask) == prefA) { uint32_t s = atomicAdd(&sh_cnt[0], 1u); if (s < CMAX) cand[0][s] = ka; }
    uint32_t kb = k1[i];
    if ((kb & pmask) == prefB) { uint32_t s = atomicAdd(&sh_cnt[1], 1u); if (s < CMAX) cand[1][s] = kb; }
  }
  __syncthreads();
  if (tid < 2) {
    uint32_t c = sh_cnt[tid]; if (c > CMAX) c = CMAX;
    uint32_t rr = tid ? remB : remA;
    uint32_t th = 0u, nd = 0u;
    for (uint32_t j = 0; j < c; ++j) {
      uint32_t kj = cand[tid][j];
      uint32_t gt = 0u;
      for (uint32_t l = 0; l < c; ++l) gt += (cand[tid][l] > kj);
      if (gt < rr) {
        uint32_t eq = 0u;
        for (uint32_t l = 0; l < c; ++l) eq += (cand[tid][l] == kj);
        if (gt + eq >= rr) { th = kj; nd = rr - gt; }
      }
    }
    sh_theta[tid] = th; sh_need[tid] = nd;
  }
  __syncthreads();
  const uint32_t thA = sh_theta[0], ndA = sh_need[0];
  const uint32_t thB = sh_theta[1], ndB = sh_need[1];

  // ---- phase 3a: compact selected cols into LDS (wave-ballot allocation) ----
#pragma unroll 1
  for (int i = 0; i < EPT; ++i) {
    const int col = i * THREADS + tid;
    {
      uint32_t ka = k0[i];
      bool inc = ka > thA;
      if (ka == thA) inc = (atomicAdd(&sh_tie[0], 1u) < ndA);
      uint64_t mb = __ballot(inc);
      uint32_t base = 0u;
      if (lane == 0) base = atomicAdd(&sh_nsel, (uint32_t)__popcll(mb));
      base = __shfl(base, 0);
      if (inc) sel[base + __popcll(mb & ((1ull << lane) - 1ull))] = (uint32_t)col;
    }
    {
      uint32_t kb = k1[i];
      bool inc = kb > thB;
      if (kb == thB) inc = (atomicAdd(&sh_tie[1], 1u) < ndB);
      uint64_t mb = __ballot(inc);
      uint32_t base = 0u;
      if (lane == 0) base = atomicAdd(&sh_nsel, (uint32_t)__popcll(mb));
      base = __shfl(base, 0);
      if (inc) sel[base + __popcll(mb & ((1ull << lane) - 1ull))] = 0x2000u | (uint32_t)col;
    }
  }
  __syncthreads();
  const uint32_t total = sh_nsel;   // == 2 * K_NEG

  const float xa0 = x_emb[r0 * 2], xa1 = x_emb[r0 * 2 + 1];
  const float xb0 = x_emb[r1 * 2], xb1 = x_emb[r1 * 2 + 1];
  const float qa = xa0 * xa0 + xa1 * xa1;
  const float qb = xb0 * xb0 + xb1 * xb1;

  // ---- phase 3b: dense sweep over the 2032 selected entries ----
  float accA = 0.0f, accB = 0.0f;
  for (uint32_t j = tid; j < total; j += THREADS) {
    uint32_t e = sel[j];
    int col = e & 0x1FFFu;
    bool isB = (e & 0x2000u) != 0u;
    float tx = t_emb[col * 2], ty = t_emb[col * 2 + 1];
    float px = isB ? xb0 : xa0;
    float py = isB ? xb1 : xa1;
    float pq = isB ? qb : qa;
    float s = sim_fast(px, py, pq, tx, ty);
    float ez = hw_exp2(s * (INV_T * INV_LN2_F));
    if (isB) accB += ez; else accA += ez;
  }
#pragma unroll
  for (int off = 32; off > 0; off >>= 1) {
    accA += __shfl_down(accA, off);
    accB += __shfl_down(accB, off);
  }
  if (lane == 0) { shA[wv] = accA; shB[wv] = accB; }
  // positives in parallel (threads 0..15)
  if (tid < 16) {
    int rowb = tid >> 3;
    int c = sh_pos[tid];
    float px = rowb ? xb0 : xa0;
    float py = rowb ? xb1 : xa1;
    float pq = rowb ? qb : qa;
    sh_pp[tid] = sim_fast(px, py, pq, t_emb[c * 2], t_emb[c * 2 + 1]);
  }
  __syncthreads();

  if (tid < 2) {
    float s = 0.0f;
#pragma unroll
    for (int w = 0; w < 16; ++w) s += tid ? shB[w] : shA[w];
    float ps = 0.0f;
#pragma unroll
    for (int p = 0; p < P_POS; ++p) ps += sh_pp[tid * P_POS + p];
    float pos = ps * (1.0f / P_POS);
    float zpos = pos * INV_T;
    float S = s + hw_exp2(zpos * INV_LN2_F) + N_PAD;
    float loss = logf(S) - zpos;
    int r = tid ? r1 : r0;
    if (row_loss) row_loss[r] = loss;
    else atomicAdd(out_atomic, loss * (1.0f / B_ROWS));
  }
}

__global__ __launch_bounds__(256) void cdr_reduce_kernel(
    const float* __restrict__ row_loss, float* __restrict__ out) {
  __shared__ float part[4];
  float s = 0.0f;
  for (int i = threadIdx.x; i < B_ROWS; i += 256) s += row_loss[i];
#pragma unroll
  for (int off = 32; off > 0; off >>= 1) s += __shfl_down(s, off);
  if ((threadIdx.x & 63) == 0) part[threadIdx.x >> 6] = s;
  __syncthreads();
  if (threadIdx.x == 0)
    out[0] = (part[0] + part[1] + part[2] + part[3]) * (1.0f / B_ROWS);
}

__global__ void cdr_zero_kernel(float* __restrict__ out) { out[0] = 0.0f; }

extern "C" void kernel_launch(void* const* d_in, const int* in_sizes, int n_in,
                              void* d_out, int out_size, void* d_ws, size_t ws_size,
                              hipStream_t stream) {
  const float* x_emb = (const float*)d_in[0];
  const float* t_emb = (const float*)d_in[1];
  const float* wf    = (const float*)d_in[2];
  const int*   pidx  = (const int*)d_in[3];
  float* out = (float*)d_out;

  // folded key: fold_in(key(0), 1) = threefry2x32((0,0), (0,1))
  uint32_t fk0 = 0u, fk1 = 1u;
  tf2x32(0u, 0u, fk0, fk1);

  const bool has_logw = (ws_size >= (size_t)(NT_COLS + B_ROWS) * sizeof(float));
  const bool has_rl   = (ws_size >= (size_t)B_ROWS * sizeof(float));

  float* logw = nullptr;
  float* row_loss = nullptr;
  if (has_logw) { logw = (float*)d_ws; row_loss = (float*)d_ws + NT_COLS; }
  else if (has_rl) { row_loss = (float*)d_ws; }

  if (has_logw) {
    hipLaunchKernelGGL(prelog_kernel, dim3(NT_COLS / 256), dim3(256), 0, stream,
                       wf, logw);
  }
  if (!row_loss) {
    hipLaunchKernelGGL(cdr_zero_kernel, dim3(1), dim3(1), 0, stream, out);
  }
  hipLaunchKernelGGL(cdr_pair_kernel, dim3(HALF_B), dim3(THREADS), 0, stream,
                     x_emb, t_emb, logw, wf, pidx, row_loss, out, fk0, fk1);
  if (row_loss) {
    hipLaunchKernelGGL(cdr_reduce_kernel, dim3(1), dim3(256), 0, stream,
                       row_loss, out);
  }
}

// Round 7
// 102.322 us; speedup vs baseline: 1.9622x; 1.1445x over previous
//
#include <hip/hip_runtime.h>
#include <cstdint>
#include <math.h>

#define B_ROWS 4096
#define HALF_B 2048
#define NT_COLS 8192
#define P_POS 8
#define K_NEG 1016
#define N_PAD 3079.0f          // B - (1+K)
#define A_C 1.57694f
#define BB_C 0.89506f
#define INV_T 6.66666666667f
#define THREADS 1024
#define EPT 8                  // NT_COLS / THREADS
#define LN2_F 0.69314718056f
#define INV_LN2_F 1.44269504089f
#define NBINS 2048
#define CMAX 128
// g = -ln(-ln u) = GUM_C - ln2 * log2(-log2(u));  GUM_C = -ln2*log2(ln2)
#define GUM_C 0.3665129206f

__device__ __forceinline__ float hw_log2(float x) { return __builtin_amdgcn_logf(x); }
__device__ __forceinline__ float hw_exp2(float x) { return __builtin_amdgcn_exp2f(x); }
__device__ __forceinline__ float hw_ln(float x) { return hw_log2(x) * LN2_F; }

__device__ __forceinline__ uint32_t mbcnt64(uint64_t m) {
  return __builtin_amdgcn_mbcnt_hi((uint32_t)(m >> 32),
         __builtin_amdgcn_mbcnt_lo((uint32_t)m, 0u));
}

// ---- Threefry-2x32, 20 rounds, exactly JAX's schedule ----
__host__ __device__ __forceinline__ void tf2x32(uint32_t k0, uint32_t k1,
                                                uint32_t& x0, uint32_t& x1) {
  const uint32_t ks2 = k0 ^ k1 ^ 0x1BD11BDAu;
  x0 += k0; x1 += k1;
#define TF_RND(r) { x0 += x1; x1 = (x1 << (r)) | (x1 >> (32 - (r))); x1 ^= x0; }
  TF_RND(13) TF_RND(15) TF_RND(26) TF_RND(6)
  x0 += k1;  x1 += ks2 + 1u;
  TF_RND(17) TF_RND(29) TF_RND(16) TF_RND(24)
  x0 += ks2; x1 += k0 + 2u;
  TF_RND(13) TF_RND(15) TF_RND(26) TF_RND(6)
  x0 += k0;  x1 += k1 + 3u;
  TF_RND(17) TF_RND(29) TF_RND(16) TF_RND(24)
  x0 += k1;  x1 += ks2 + 4u;
  TF_RND(13) TF_RND(15) TF_RND(26) TF_RND(6)
  x0 += ks2; x1 += k0 + 5u;
#undef TF_RND
}

__device__ __forceinline__ float sim_fast(float x0, float x1, float xsq,
                                          float tx, float ty) {
  float tsq = tx * tx + ty * ty;
  float d2 = fmaxf(xsq + tsq - 2.0f * (x0 * tx + x1 * ty), 1e-12f);
  return 1.0f / (1.0f + A_C * hw_exp2(BB_C * hw_log2(d2)));
}

__device__ __forceinline__ uint32_t make_key(uint32_t bits, float lw) {
  float f = __uint_as_float((bits >> 9) | 0x3f800000u) - 1.0f;
  float u = fmaxf(f, 1e-20f);
  float g = GUM_C - LN2_F * hw_log2(-hw_log2(u));
  uint32_t sb = __float_as_uint(lw + g);
  return sb ^ (0x80000000u | (uint32_t)((int32_t)sb >> 31));
}

__global__ void prelog_kernel(const float* __restrict__ wf,
                              float* __restrict__ logw) {
  int i = blockIdx.x * 256 + threadIdx.x;
  if (i < NT_COLS) logw[i] = 0.75f * logf(wf[i]);
}

// one radix pass over 11 bits at SHIFT; GUARDED = prefix-filter active
template <int SHIFT, bool GUARDED>
__device__ __forceinline__ void radix_pass(
    const uint32_t* k0, const uint32_t* k1, uint32_t (*hist)[NBINS],
    uint32_t& prefA, uint32_t& remA, uint32_t& prefB, uint32_t& remB,
    uint32_t pmask, uint32_t* wsumA, uint32_t* wsumB,
    volatile uint32_t* sh_scal, int tid, int lane, int wv) {
#pragma unroll
  for (int i = 0; i < EPT; ++i) {
    uint32_t ka = k0[i];
    if (!GUARDED || (ka & pmask) == prefA)
      atomicAdd(&hist[0][(ka >> SHIFT) & 0x7FFu], 1u);
    uint32_t kb = k1[i];
    if (!GUARDED || (kb & pmask) == prefB)
      atomicAdd(&hist[1][(kb >> SHIFT) & 0x7FFu], 1u);
  }
  __syncthreads();
  uint2 av = ((uint2*)hist[0])[tid];
  uint2 bv = ((uint2*)hist[1])[tid];
  if (!GUARDED) {   // re-zero for the next pass inside the same barrier window
    ((uint2*)hist[0])[tid] = make_uint2(0u, 0u);
    ((uint2*)hist[1])[tid] = make_uint2(0u, 0u);
  }
  uint32_t Pa = av.x + av.y, Pb = bv.x + bv.y;
  uint32_t ia = Pa, ib = Pb;
#pragma unroll
  for (int off = 1; off < 64; off <<= 1) {
    uint32_t ua = __shfl_down(ia, off), ub = __shfl_down(ib, off);
    if (lane + off < 64) { ia += ua; ib += ub; }
  }
  if (lane == 0) { wsumA[wv] = ia; wsumB[wv] = ib; }
  __syncthreads();
  // in-wave suffix over the 16 wave totals (no extra barrier)
  uint32_t ta = wsumA[lane & 15], tb = wsumB[lane & 15];
  uint32_t oa = ta, ob = tb;
#pragma unroll
  for (int off = 1; off < 16; off <<= 1) {
    uint32_t ua = __shfl_down(ta, off), ub = __shfl_down(tb, off);
    if (lane + off < 16) { ta += ua; tb += ub; }
  }
  uint32_t eA = (uint32_t)__builtin_amdgcn_readlane((int)(ta - oa), wv);
  uint32_t eB = (uint32_t)__builtin_amdgcn_readlane((int)(tb - ob), wv);
  uint32_t Sa = eA + (ia - Pa);
  uint32_t Sb = eB + (ib - Pb);
  {
    uint32_t gt0 = av.y + Sa, ge0 = Pa + Sa, gt1 = Sa, ge1 = av.y + Sa;
    if (ge0 >= remA && gt0 < remA) { sh_scal[0] = prefA | ((uint32_t)(2 * tid) << SHIFT); sh_scal[1] = remA - gt0; }
    if (ge1 >= remA && gt1 < remA) { sh_scal[0] = prefA | ((uint32_t)(2 * tid + 1) << SHIFT); sh_scal[1] = remA - gt1; }
  }
  {
    uint32_t gt0 = bv.y + Sb, ge0 = Pb + Sb, gt1 = Sb, ge1 = bv.y + Sb;
    if (ge0 >= remB && gt0 < remB) { sh_scal[2] = prefB | ((uint32_t)(2 * tid) << SHIFT); sh_scal[3] = remB - gt0; }
    if (ge1 >= remB && gt1 < remB) { sh_scal[2] = prefB | ((uint32_t)(2 * tid + 1) << SHIFT); sh_scal[3] = remB - gt1; }
  }
  __syncthreads();
  prefA = sh_scal[0]; remA = sh_scal[1];
  prefB = sh_scal[2]; remB = sh_scal[3];
}

__global__ __launch_bounds__(THREADS, 8) void cdr_pair_kernel(
    const float* __restrict__ x_emb, const float* __restrict__ t_emb,
    const float* __restrict__ logw, const float* __restrict__ wf,
    const int* __restrict__ pos_idx,
    float* __restrict__ row_loss, float* __restrict__ out_atomic,
    uint32_t fk0, uint32_t fk1) {
  __shared__ uint32_t hist[2][NBINS];   // 16 KB
  __shared__ uint32_t sel[2048];        // 8 KB (2032 used)
  __shared__ uint32_t candK[2][CMAX];   // 1 KB
  __shared__ uint16_t candC[2][CMAX];   // 0.5 KB
  __shared__ uint32_t wsumA[16], wsumB[16];
  __shared__ uint32_t sh_scal[4];
  __shared__ uint32_t sh_cnt[2], sh_tie[2], sh_nsel;
  __shared__ uint32_t sh_theta[2], sh_need[2];
  __shared__ int sh_pos[2 * P_POS];
  __shared__ float shA[16], shB[16], sh_pp[16];

  const int r0 = blockIdx.x;            // 0..2047
  const int r1 = r0 + HALF_B;
  const int tid = threadIdx.x;
  const int lane = tid & 63;
  const int wv = tid >> 6;

  // init: zero hist, load pos, zero counters
  ((uint2*)hist[0])[tid] = make_uint2(0u, 0u);
  ((uint2*)hist[1])[tid] = make_uint2(0u, 0u);
  if (tid < P_POS) sh_pos[tid] = pos_idx[r0 * P_POS + tid];
  else if (tid < 2 * P_POS) sh_pos[tid] = pos_idx[r1 * P_POS + (tid - P_POS)];
  if (tid == 0) sh_nsel = 0u;
  if (tid < 2) { sh_cnt[tid] = 0u; sh_tie[tid] = 0u; }
  __syncthreads();

  uint32_t m0 = 0u, m1 = 0u;
#pragma unroll
  for (int p = 0; p < P_POS; ++p) {
    int c0 = sh_pos[p], c1 = sh_pos[P_POS + p];
    if ((c0 & (THREADS - 1)) == tid) m0 |= 1u << (c0 >> 10);
    if ((c1 & (THREADS - 1)) == tid) m1 |= 1u << (c1 >> 10);
  }

  // ---- phase 1: one threefry feeds both rows; keys stay in VGPRs ----
  uint32_t k0[EPT], k1[EPT];
  const uint32_t H = 16777216u;   // (B*NT)/2
#pragma unroll
  for (int i = 0; i < EPT; ++i) {
    const int col = i * THREADS + tid;
    const uint32_t n = (uint32_t)(r0 * NT_COLS + col);
    uint32_t xa = n, xb = n + H;
    tf2x32(fk0, fk1, xa, xb);
    const float lw = logw ? logw[col] : 0.75f * hw_ln(wf[col]);
    uint32_t ka = make_key(xa, lw);
    uint32_t kb = make_key(xb, lw);
    k0[i] = ((m0 >> i) & 1u) ? 0u : ka;
    k1[i] = ((m1 >> i) & 1u) ? 0u : kb;
  }
  __syncthreads();

  // ---- phase 2: two 11-bit radix passes, both rows in parallel ----
  uint32_t prefA = 0u, prefB = 0u, remA = K_NEG, remB = K_NEG;
  radix_pass<21, false>(k0, k1, hist, prefA, remA, prefB, remB,
                        0u, wsumA, wsumB, sh_scal, tid, lane, wv);
  radix_pass<10, true>(k0, k1, hist, prefA, remA, prefB, remB,
                       0xFFE00000u, wsumA, wsumB, sh_scal, tid, lane, wv);
  const uint32_t PM22 = 0xFFFFFC00u;

  // ---- phase 3a: ONE sweep: compact definite-selected; collect candidates ----
#pragma unroll
  for (int i = 0; i < EPT; ++i) {
    const int col = i * THREADS + tid;
#pragma unroll
    for (int rsb = 0; rsb < 2; ++rsb) {
      uint32_t k = rsb ? k1[i] : k0[i];
      uint32_t pref = rsb ? prefB : prefA;
      uint32_t p22 = k & PM22;
      bool def = p22 > pref;
      uint64_t mb = __ballot(def);
      uint32_t base = 0u;
      if (lane == 0) base = atomicAdd(&sh_nsel, (uint32_t)__popcll(mb));
      base = (uint32_t)__builtin_amdgcn_readfirstlane((int)base);
      if (def) sel[base + mbcnt64(mb)] = (uint32_t)col | ((uint32_t)rsb << 13);
      if (p22 == pref) {
        uint32_t s = atomicAdd(&sh_cnt[rsb], 1u);
        if (s < CMAX) { candK[rsb][s] = k; candC[rsb][s] = (uint16_t)col; }
      }
    }
  }
  __syncthreads();

  // ---- phase 3b: resolve exact theta among the few prefix-tied candidates ----
  if (tid < 2) {
    uint32_t c = sh_cnt[tid]; if (c > CMAX) c = CMAX;
    uint32_t rr = tid ? remB : remA;
    uint32_t th = 0u, nd = 0u;
    for (uint32_t j = 0; j < c; ++j) {
      uint32_t kj = candK[tid][j];
      uint32_t gt = 0u, eq = 0u;
      for (uint32_t l = 0; l < c; ++l) { gt += (candK[tid][l] > kj); eq += (candK[tid][l] == kj); }
      if (gt < rr && gt + eq >= rr) { th = kj; nd = rr - gt; }
    }
    sh_theta[tid] = th; sh_need[tid] = nd;
  }
  __syncthreads();

  // ---- phase 3c: append boundary candidates ----
  if (tid < 2 * CMAX) {
    const int rsb = tid >> 7;
    const uint32_t j = tid & (CMAX - 1);
    uint32_t c = sh_cnt[rsb]; if (c > CMAX) c = CMAX;
    if (j < c) {
      uint32_t k = candK[rsb][j];
      uint32_t th = sh_theta[rsb];
      bool inc = (k > th);
      if (k == th) inc = (atomicAdd(&sh_tie[rsb], 1u) < sh_need[rsb]);
      if (inc) {
        uint32_t s = atomicAdd(&sh_nsel, 1u);
        sel[s] = (uint32_t)candC[rsb][j] | ((uint32_t)rsb << 13);
      }
    }
  }
  __syncthreads();
  const uint32_t total = sh_nsel;   // == 2 * K_NEG

  const float xa0 = x_emb[r0 * 2], xa1 = x_emb[r0 * 2 + 1];
  const float xb0 = x_emb[r1 * 2], xb1 = x_emb[r1 * 2 + 1];
  const float qa = xa0 * xa0 + xa1 * xa1;
  const float qb = xb0 * xb0 + xb1 * xb1;
  const float2* temb2 = (const float2*)t_emb;

  // ---- phase 4: dense sweep over the 2032 selected entries ----
  float accA = 0.0f, accB = 0.0f;
  for (uint32_t j = tid; j < total; j += THREADS) {
    uint32_t e = sel[j];
    int col = e & 0x1FFFu;
    bool isB = (e & 0x2000u) != 0u;
    float2 t = temb2[col];
    float px = isB ? xb0 : xa0;
    float py = isB ? xb1 : xa1;
    float pq = isB ? qb : qa;
    float s = sim_fast(px, py, pq, t.x, t.y);
    float ez = hw_exp2(s * (INV_T * INV_LN2_F));
    if (isB) accB += ez; else accA += ez;
  }
#pragma unroll
  for (int off = 32; off > 0; off >>= 1) {
    accA += __shfl_down(accA, off);
    accB += __shfl_down(accB, off);
  }
  if (lane == 0) { shA[wv] = accA; shB[wv] = accB; }
  if (tid < 16) {
    int rowb = tid >> 3;
    int c = sh_pos[tid];
    float2 t = temb2[c];
    float px = rowb ? xb0 : xa0;
    float py = rowb ? xb1 : xa1;
    float pq = rowb ? qb : qa;
    sh_pp[tid] = sim_fast(px, py, pq, t.x, t.y);
  }
  __syncthreads();

  if (tid < 2) {
    float s = 0.0f;
#pragma unroll
    for (int w = 0; w < 16; ++w) s += tid ? shB[w] : shA[w];
    float ps = 0.0f;
#pragma unroll
    for (int p = 0; p < P_POS; ++p) ps += sh_pp[tid * P_POS + p];
    float pos = ps * (1.0f / P_POS);
    float zpos = pos * INV_T;
    float S = s + hw_exp2(zpos * INV_LN2_F) + N_PAD;
    float loss = logf(S) - zpos;
    int r = tid ? r1 : r0;
    if (row_loss) row_loss[r] = loss;
    else atomicAdd(out_atomic, loss * (1.0f / B_ROWS));
  }
}

__global__ __launch_bounds__(256) void cdr_reduce_kernel(
    const float* __restrict__ row_loss, float* __restrict__ out) {
  __shared__ float part[4];
  float s = 0.0f;
  for (int i = threadIdx.x; i < B_ROWS; i += 256) s += row_loss[i];
#pragma unroll
  for (int off = 32; off > 0; off >>= 1) s += __shfl_down(s, off);
  if ((threadIdx.x & 63) == 0) part[threadIdx.x >> 6] = s;
  __syncthreads();
  if (threadIdx.x == 0)
    out[0] = (part[0] + part[1] + part[2] + part[3]) * (1.0f / B_ROWS);
}

__global__ void cdr_zero_kernel(float* __restrict__ out) { out[0] = 0.0f; }

extern "C" void kernel_launch(void* const* d_in, const int* in_sizes, int n_in,
                              void* d_out, int out_size, void* d_ws, size_t ws_size,
                              hipStream_t stream) {
  const float* x_emb = (const float*)d_in[0];
  const float* t_emb = (const float*)d_in[1];
  const float* wf    = (const float*)d_in[2];
  const int*   pidx  = (const int*)d_in[3];
  float* out = (float*)d_out;

  uint32_t fk0 = 0u, fk1 = 1u;
  tf2x32(0u, 0u, fk0, fk1);

  const bool has_logw = (ws_size >= (size_t)(NT_COLS + B_ROWS) * sizeof(float));
  const bool has_rl   = (ws_size >= (size_t)B_ROWS * sizeof(float));

  float* logw = nullptr;
  float* row_loss = nullptr;
  if (has_logw) { logw = (float*)d_ws; row_loss = (float*)d_ws + NT_COLS; }
  else if (has_rl) { row_loss = (float*)d_ws; }

  if (has_logw) {
    hipLaunchKernelGGL(prelog_kernel, dim3(NT_COLS / 256), dim3(256), 0, stream,
                       wf, logw);
  }
  if (!row_loss) {
    hipLaunchKernelGGL(cdr_zero_kernel, dim3(1), dim3(1), 0, stream, out);
  }
  hipLaunchKernelGGL(cdr_pair_kernel, dim3(HALF_B), dim3(THREADS), 0, stream,
                     x_emb, t_emb, logw, wf, pidx, row_loss, out, fk0, fk1);
  if (row_loss) {
    hipLaunchKernelGGL(cdr_reduce_kernel, dim3(1), dim3(256), 0, stream,
                       row_loss, out);
  }
}

// Round 8
// 91.926 us; speedup vs baseline: 2.1841x; 1.1131x over previous
//
#include <hip/hip_runtime.h>
#include <cstdint>
#include <math.h>

#define B_ROWS 4096
#define HALF_B 2048
#define NT_COLS 8192
#define P_POS 8
#define K_NEG 1016
#define N_PAD 3079.0f          // B - (1+K)
#define A_C 1.57694f
#define BB_C 0.89506f
#define INV_T 6.66666666667f
#define THREADS 1024
#define EPT 8                  // NT_COLS / THREADS
#define LN2_F 0.69314718056f
#define INV_LN2_F 1.44269504089f
#define NBINS 2048
#define CMAX 128

__device__ __forceinline__ float hw_log2(float x) { return __builtin_amdgcn_logf(x); }
__device__ __forceinline__ float hw_exp2(float x) { return __builtin_amdgcn_exp2f(x); }

__device__ __forceinline__ uint32_t mbcnt64(uint64_t m) {
  return __builtin_amdgcn_mbcnt_hi((uint32_t)(m >> 32),
         __builtin_amdgcn_mbcnt_lo((uint32_t)m, 0u));
}

// ---- Threefry-2x32, 20 rounds, exactly JAX's schedule ----
__host__ __device__ __forceinline__ void tf2x32(uint32_t k0, uint32_t k1,
                                                uint32_t& x0, uint32_t& x1) {
  const uint32_t ks2 = k0 ^ k1 ^ 0x1BD11BDAu;
  x0 += k0; x1 += k1;
#define TF_RND(r) { x0 += x1; x1 = (x1 << (r)) | (x1 >> (32 - (r))); x1 ^= x0; }
  TF_RND(13) TF_RND(15) TF_RND(26) TF_RND(6)
  x0 += k1;  x1 += ks2 + 1u;
  TF_RND(17) TF_RND(29) TF_RND(16) TF_RND(24)
  x0 += ks2; x1 += k0 + 2u;
  TF_RND(13) TF_RND(15) TF_RND(26) TF_RND(6)
  x0 += k0;  x1 += k1 + 3u;
  TF_RND(17) TF_RND(29) TF_RND(16) TF_RND(24)
  x0 += k1;  x1 += ks2 + 4u;
  TF_RND(13) TF_RND(15) TF_RND(26) TF_RND(6)
  x0 += ks2; x1 += k0 + 5u;
#undef TF_RND
}

__device__ __forceinline__ float sim_fast(float x0, float x1, float xsq,
                                          float tx, float ty) {
  float tsq = tx * tx + ty * ty;
  float d2 = fmaxf(xsq + tsq - 2.0f * (x0 * tx + x1 * ty), 1e-12f);
  return 1.0f / (1.0f + A_C * hw_exp2(BB_C * hw_log2(d2)));
}

// t = (-ln u) * wf^-0.75 = exp(-score): rank DESC by score == rank ASC by t.
// w75n = -wf^-0.75 (negative), log2(u) negative -> t > 0. Flip bits so the
// existing "select K largest keys" radix machinery is unchanged.
__device__ __forceinline__ uint32_t make_key(uint32_t bits, float w75n) {
  float f = __uint_as_float((bits >> 9) | 0x3f800000u) - 1.0f;
  float u = fmaxf(f, 1e-20f);           // JAX uniform(1e-20, 1.0)
  float t = hw_log2(u) * w75n;
  return ~__float_as_uint(t);
}

__global__ void prew_kernel(const float* __restrict__ wf,
                            float* __restrict__ w75n) {
  int i = blockIdx.x * 256 + threadIdx.x;
  if (i < NT_COLS) w75n[i] = -powf(wf[i], -0.75f);
}

// post-histogram scan + boundary find for one 11-bit digit at SHIFT
template <int SHIFT>
__device__ __forceinline__ void scan_pass(
    uint32_t (*hist)[NBINS], bool rezero,
    uint32_t& prefA, uint32_t& remA, uint32_t& prefB, uint32_t& remB,
    uint32_t* wsumA, uint32_t* wsumB,
    volatile uint32_t* sh_scal, int tid, int lane, int wv) {
  __syncthreads();
  uint2 av = ((uint2*)hist[0])[tid];
  uint2 bv = ((uint2*)hist[1])[tid];
  if (rezero) {
    ((uint2*)hist[0])[tid] = make_uint2(0u, 0u);
    ((uint2*)hist[1])[tid] = make_uint2(0u, 0u);
  }
  uint32_t Pa = av.x + av.y, Pb = bv.x + bv.y;
  uint32_t ia = Pa, ib = Pb;
#pragma unroll
  for (int off = 1; off < 64; off <<= 1) {
    uint32_t ua = __shfl_down(ia, off), ub = __shfl_down(ib, off);
    if (lane + off < 64) { ia += ua; ib += ub; }
  }
  if (lane == 0) { wsumA[wv] = ia; wsumB[wv] = ib; }
  __syncthreads();
  uint32_t ta = wsumA[lane & 15], tb = wsumB[lane & 15];
  uint32_t oa = ta, ob = tb;
#pragma unroll
  for (int off = 1; off < 16; off <<= 1) {
    uint32_t ua = __shfl_down(ta, off), ub = __shfl_down(tb, off);
    if (lane + off < 16) { ta += ua; tb += ub; }
  }
  uint32_t eA = (uint32_t)__builtin_amdgcn_readlane((int)(ta - oa), wv);
  uint32_t eB = (uint32_t)__builtin_amdgcn_readlane((int)(tb - ob), wv);
  uint32_t Sa = eA + (ia - Pa);
  uint32_t Sb = eB + (ib - Pb);
  {
    uint32_t gt0 = av.y + Sa, ge0 = Pa + Sa, gt1 = Sa, ge1 = av.y + Sa;
    if (ge0 >= remA && gt0 < remA) { sh_scal[0] = prefA | ((uint32_t)(2 * tid) << SHIFT); sh_scal[1] = remA - gt0; }
    if (ge1 >= remA && gt1 < remA) { sh_scal[0] = prefA | ((uint32_t)(2 * tid + 1) << SHIFT); sh_scal[1] = remA - gt1; }
  }
  {
    uint32_t gt0 = bv.y + Sb, ge0 = Pb + Sb, gt1 = Sb, ge1 = bv.y + Sb;
    if (ge0 >= remB && gt0 < remB) { sh_scal[2] = prefB | ((uint32_t)(2 * tid) << SHIFT); sh_scal[3] = remB - gt0; }
    if (ge1 >= remB && gt1 < remB) { sh_scal[2] = prefB | ((uint32_t)(2 * tid + 1) << SHIFT); sh_scal[3] = remB - gt1; }
  }
  __syncthreads();
  prefA = sh_scal[0]; remA = sh_scal[1];
  prefB = sh_scal[2]; remB = sh_scal[3];
}

__global__ __launch_bounds__(THREADS, 8) void cdr_pair_kernel(
    const float* __restrict__ x_emb, const float* __restrict__ t_emb,
    const float* __restrict__ w75n, const float* __restrict__ wf,
    const int* __restrict__ pos_idx,
    float* __restrict__ row_loss, float* __restrict__ out_atomic,
    uint32_t fk0, uint32_t fk1) {
  __shared__ uint32_t hist[2][NBINS];   // 16 KB
  __shared__ uint32_t sel[2048];        // 8 KB (2032 used)
  __shared__ uint32_t candK[2][CMAX];   // 1 KB
  __shared__ uint16_t candC[2][CMAX];   // 0.5 KB
  __shared__ uint32_t wsumA[16], wsumB[16];
  __shared__ uint32_t sh_scal[4];
  __shared__ uint32_t sh_cnt[2], sh_tie[2], sh_nsel;
  __shared__ uint32_t sh_theta[2], sh_need[2];
  __shared__ int sh_pos[2 * P_POS];
  __shared__ float shA[16], shB[16], sh_pp[16];

  const int r0 = blockIdx.x;            // 0..2047
  const int r1 = r0 + HALF_B;
  const int tid = threadIdx.x;
  const int lane = tid & 63;
  const int wv = tid >> 6;

  ((uint2*)hist[0])[tid] = make_uint2(0u, 0u);
  ((uint2*)hist[1])[tid] = make_uint2(0u, 0u);
  if (tid < P_POS) sh_pos[tid] = pos_idx[r0 * P_POS + tid];
  else if (tid < 2 * P_POS) sh_pos[tid] = pos_idx[r1 * P_POS + (tid - P_POS)];
  if (tid == 0) sh_nsel = 0u;
  if (tid < 2) { sh_cnt[tid] = 0u; sh_tie[tid] = 0u; }
  __syncthreads();

  uint32_t m0 = 0u, m1 = 0u;
#pragma unroll
  for (int p = 0; p < P_POS; ++p) {
    int c0 = sh_pos[p], c1 = sh_pos[P_POS + p];
    if ((c0 & (THREADS - 1)) == tid) m0 |= 1u << (c0 >> 10);
    if ((c1 & (THREADS - 1)) == tid) m1 |= 1u << (c1 >> 10);
  }

  // ---- phase 1: threefry -> keys (regs) with FUSED pass-1 histogram ----
  uint32_t k0[EPT], k1[EPT];
  const uint32_t H = 16777216u;   // (B*NT)/2
#pragma unroll
  for (int i = 0; i < EPT; ++i) {
    const int col = i * THREADS + tid;
    const uint32_t n = (uint32_t)(r0 * NT_COLS + col);
    uint32_t xa = n, xb = n + H;
    tf2x32(fk0, fk1, xa, xb);
    const float wn = w75n ? w75n[col]
                          : -hw_exp2(-0.75f * hw_log2(wf[col]));
    uint32_t ka = make_key(xa, wn);
    uint32_t kb = make_key(xb, wn);
    ka = ((m0 >> i) & 1u) ? 0u : ka;
    kb = ((m1 >> i) & 1u) ? 0u : kb;
    k0[i] = ka; k1[i] = kb;
    atomicAdd(&hist[0][ka >> 21], 1u);
    atomicAdd(&hist[1][kb >> 21], 1u);
  }

  // ---- phase 2: digit 1 scan, then guarded digit 2 ----
  uint32_t prefA = 0u, prefB = 0u, remA = K_NEG, remB = K_NEG;
  scan_pass<21>(hist, true, prefA, remA, prefB, remB,
                wsumA, wsumB, sh_scal, tid, lane, wv);
  const uint32_t PM11 = 0xFFE00000u;
#pragma unroll
  for (int i = 0; i < EPT; ++i) {
    uint32_t ka = k0[i];
    if ((ka & PM11) == prefA) atomicAdd(&hist[0][(ka >> 10) & 0x7FFu], 1u);
    uint32_t kb = k1[i];
    if ((kb & PM11) == prefB) atomicAdd(&hist[1][(kb >> 10) & 0x7FFu], 1u);
  }
  scan_pass<10>(hist, false, prefA, remA, prefB, remB,
                wsumA, wsumB, sh_scal, tid, lane, wv);
  const uint32_t PM22 = 0xFFFFFC00u;

  // ---- phase 3a: one sweep: compact definite-selected; collect candidates ----
#pragma unroll
  for (int i = 0; i < EPT; ++i) {
    const int col = i * THREADS + tid;
#pragma unroll
    for (int rsb = 0; rsb < 2; ++rsb) {
      uint32_t k = rsb ? k1[i] : k0[i];
      uint32_t pref = rsb ? prefB : prefA;
      uint32_t p22 = k & PM22;
      bool def = p22 > pref;
      uint64_t mb = __ballot(def);
      uint32_t base = 0u;
      if (lane == 0) base = atomicAdd(&sh_nsel, (uint32_t)__popcll(mb));
      base = (uint32_t)__builtin_amdgcn_readfirstlane((int)base);
      if (def) sel[base + mbcnt64(mb)] = (uint32_t)col | ((uint32_t)rsb << 13);
      if (p22 == pref) {
        uint32_t s = atomicAdd(&sh_cnt[rsb], 1u);
        if (s < CMAX) { candK[rsb][s] = k; candC[rsb][s] = (uint16_t)col; }
      }
    }
  }
  __syncthreads();

  // ---- phase 3b: resolve exact theta among the prefix-tied candidates ----
  if (tid < 2) {
    uint32_t c = sh_cnt[tid]; if (c > CMAX) c = CMAX;
    uint32_t rr = tid ? remB : remA;
    uint32_t th = 0u, nd = 0u;
    for (uint32_t j = 0; j < c; ++j) {
      uint32_t kj = candK[tid][j];
      uint32_t gt = 0u, eq = 0u;
      for (uint32_t l = 0; l < c; ++l) { gt += (candK[tid][l] > kj); eq += (candK[tid][l] == kj); }
      if (gt < rr && gt + eq >= rr) { th = kj; nd = rr - gt; }
    }
    sh_theta[tid] = th; sh_need[tid] = nd;
  }
  __syncthreads();

  // ---- phase 3c: append boundary candidates ----
  if (tid < 2 * CMAX) {
    const int rsb = tid >> 7;
    const uint32_t j = tid & (CMAX - 1);
    uint32_t c = sh_cnt[rsb]; if (c > CMAX) c = CMAX;
    if (j < c) {
      uint32_t k = candK[rsb][j];
      uint32_t th = sh_theta[rsb];
      bool inc = (k > th);
      if (k == th) inc = (atomicAdd(&sh_tie[rsb], 1u) < sh_need[rsb]);
      if (inc) {
        uint32_t s = atomicAdd(&sh_nsel, 1u);
        sel[s] = (uint32_t)candC[rsb][j] | ((uint32_t)rsb << 13);
      }
    }
  }
  __syncthreads();
  const uint32_t total = sh_nsel;   // == 2 * K_NEG

  const float xa0 = x_emb[r0 * 2], xa1 = x_emb[r0 * 2 + 1];
  const float xb0 = x_emb[r1 * 2], xb1 = x_emb[r1 * 2 + 1];
  const float qa = xa0 * xa0 + xa1 * xa1;
  const float qb = xb0 * xb0 + xb1 * xb1;
  const float2* temb2 = (const float2*)t_emb;

  // ---- phase 4: dense sweep over the 2032 selected entries ----
  float accA = 0.0f, accB = 0.0f;
  for (uint32_t j = tid; j < total; j += THREADS) {
    uint32_t e = sel[j];
    int col = e & 0x1FFFu;
    bool isB = (e & 0x2000u) != 0u;
    float2 t = temb2[col];
    float px = isB ? xb0 : xa0;
    float py = isB ? xb1 : xa1;
    float pq = isB ? qb : qa;
    float s = sim_fast(px, py, pq, t.x, t.y);
    float ez = hw_exp2(s * (INV_T * INV_LN2_F));
    if (isB) accB += ez; else accA += ez;
  }
#pragma unroll
  for (int off = 32; off > 0; off >>= 1) {
    accA += __shfl_down(accA, off);
    accB += __shfl_down(accB, off);
  }
  if (lane == 0) { shA[wv] = accA; shB[wv] = accB; }
  if (tid < 16) {
    int rowb = tid >> 3;
    int c = sh_pos[tid];
    float2 t = temb2[c];
    float px = rowb ? xb0 : xa0;
    float py = rowb ? xb1 : xa1;
    float pq = rowb ? qb : qa;
    sh_pp[tid] = sim_fast(px, py, pq, t.x, t.y);
  }
  __syncthreads();

  if (tid < 2) {
    float s = 0.0f;
#pragma unroll
    for (int w = 0; w < 16; ++w) s += tid ? shB[w] : shA[w];
    float ps = 0.0f;
#pragma unroll
    for (int p = 0; p < P_POS; ++p) ps += sh_pp[tid * P_POS + p];
    float pos = ps * (1.0f / P_POS);
    float zpos = pos * INV_T;
    float S = s + hw_exp2(zpos * INV_LN2_F) + N_PAD;
    float loss = logf(S) - zpos;
    int r = tid ? r1 : r0;
    if (row_loss) row_loss[r] = loss;
    else atomicAdd(out_atomic, loss * (1.0f / B_ROWS));
  }
}

__global__ __launch_bounds__(256) void cdr_reduce_kernel(
    const float* __restrict__ row_loss, float* __restrict__ out) {
  __shared__ float part[4];
  float s = 0.0f;
  for (int i = threadIdx.x; i < B_ROWS; i += 256) s += row_loss[i];
#pragma unroll
  for (int off = 32; off > 0; off >>= 1) s += __shfl_down(s, off);
  if ((threadIdx.x & 63) == 0) part[threadIdx.x >> 6] = s;
  __syncthreads();
  if (threadIdx.x == 0)
    out[0] = (part[0] + part[1] + part[2] + part[3]) * (1.0f / B_ROWS);
}

__global__ void cdr_zero_kernel(float* __restrict__ out) { out[0] = 0.0f; }

extern "C" void kernel_launch(void* const* d_in, const int* in_sizes, int n_in,
                              void* d_out, int out_size, void* d_ws, size_t ws_size,
                              hipStream_t stream) {
  const float* x_emb = (const float*)d_in[0];
  const float* t_emb = (const float*)d_in[1];
  const float* wf    = (const float*)d_in[2];
  const int*   pidx  = (const int*)d_in[3];
  float* out = (float*)d_out;

  uint32_t fk0 = 0u, fk1 = 1u;
  tf2x32(0u, 0u, fk0, fk1);

  const bool has_w75 = (ws_size >= (size_t)(NT_COLS + B_ROWS) * sizeof(float));
  const bool has_rl  = (ws_size >= (size_t)B_ROWS * sizeof(float));

  float* w75n = nullptr;
  float* row_loss = nullptr;
  if (has_w75) { w75n = (float*)d_ws; row_loss = (float*)d_ws + NT_COLS; }
  else if (has_rl) { row_loss = (float*)d_ws; }

  if (has_w75) {
    hipLaunchKernelGGL(prew_kernel, dim3(NT_COLS / 256), dim3(256), 0, stream,
                       wf, w75n);
  }
  if (!row_loss) {
    hipLaunchKernelGGL(cdr_zero_kernel, dim3(1), dim3(1), 0, stream, out);
  }
  hipLaunchKernelGGL(cdr_pair_kernel, dim3(HALF_B), dim3(THREADS), 0, stream,
                     x_emb, t_emb, w75n, wf, pidx, row_loss, out, fk0, fk1);
  if (row_loss) {
    hipLaunchKernelGGL(cdr_reduce_kernel, dim3(1), dim3(256), 0, stream,
                       row_loss, out);
  }
}

// Round 9
// 85.430 us; speedup vs baseline: 2.3502x; 1.0760x over previous
//
#include <hip/hip_runtime.h>
#include <cstdint>
#include <math.h>

#define B_ROWS 4096
#define HALF_B 2048
#define NT_COLS 8192
#define P_POS 8
#define K_NEG 1016
#define N_PAD 3079.0f          // B - (1+K)
#define A_C 1.57694f
#define BB_C 0.89506f
#define INV_T 6.66666666667f
#define THREADS 1024
#define EPT 8                  // NT_COLS / THREADS
#define LN2_F 0.69314718056f
#define INV_LN2_F 1.44269504089f
#define NBINS 2048
#define CMAX 128

__device__ __forceinline__ float hw_log2(float x) { return __builtin_amdgcn_logf(x); }
__device__ __forceinline__ float hw_exp2(float x) { return __builtin_amdgcn_exp2f(x); }

__device__ __forceinline__ uint32_t mbcnt64(uint64_t m) {
  return __builtin_amdgcn_mbcnt_hi((uint32_t)(m >> 32),
         __builtin_amdgcn_mbcnt_lo((uint32_t)m, 0u));
}

// 1-instruction rotate on device (v_alignbit_b32), plain on host
__host__ __device__ __forceinline__ uint32_t rotl32(uint32_t x, int r) {
#ifdef __HIP_DEVICE_COMPILE__
  return __builtin_amdgcn_alignbit(x, x, (uint32_t)(32 - r));
#else
  return (x << r) | (x >> (32 - r));
#endif
}

// ---- Threefry-2x32, 20 rounds, exactly JAX's schedule ----
__host__ __device__ __forceinline__ void tf2x32(uint32_t k0, uint32_t k1,
                                                uint32_t& x0, uint32_t& x1) {
  const uint32_t ks2 = k0 ^ k1 ^ 0x1BD11BDAu;
  x0 += k0; x1 += k1;
#define TF_RND(r) { x0 += x1; x1 = rotl32(x1, r); x1 ^= x0; }
  TF_RND(13) TF_RND(15) TF_RND(26) TF_RND(6)
  x0 += k1;  x1 += ks2 + 1u;
  TF_RND(17) TF_RND(29) TF_RND(16) TF_RND(24)
  x0 += ks2; x1 += k0 + 2u;
  TF_RND(13) TF_RND(15) TF_RND(26) TF_RND(6)
  x0 += k0;  x1 += k1 + 3u;
  TF_RND(17) TF_RND(29) TF_RND(16) TF_RND(24)
  x0 += k1;  x1 += ks2 + 4u;
  TF_RND(13) TF_RND(15) TF_RND(26) TF_RND(6)
  x0 += ks2; x1 += k0 + 5u;
#undef TF_RND
}

__device__ __forceinline__ float sim_fast(float x0, float x1, float xsq,
                                          float tx, float ty) {
  float tsq = tx * tx + ty * ty;
  float d2 = fmaxf(xsq + tsq - 2.0f * (x0 * tx + x1 * ty), 1e-12f);
  return 1.0f / (1.0f + A_C * hw_exp2(BB_C * hw_log2(d2)));
}

// t = (-ln u) * wf^-0.75 = exp(-score): rank DESC by score == rank ASC by t.
// u==0 (prob 2^-23) -> t=+inf -> lowest priority; JAX's clamp gives a finite
// but equally never-selected value, so selection is identical. Flip bits so
// "select K largest keys" machinery is unchanged.
__device__ __forceinline__ uint32_t make_key(uint32_t bits, float w75n) {
  float f = __uint_as_float((bits >> 9) | 0x3f800000u) - 1.0f;   // u in [0,1)
  float t = hw_log2(f) * w75n;                                   // >0 (w75n<0)
  return ~__float_as_uint(t);
}

__global__ void prew_kernel(const float* __restrict__ wf,
                            float* __restrict__ w75n) {
  int i = blockIdx.x * 256 + threadIdx.x;
  if (i < NT_COLS) w75n[i] = -powf(wf[i], -0.75f);
}

// post-histogram scan + boundary find for one 11-bit digit at SHIFT.
// hist is PACKED: row A counts in low 16 bits, row B in high 16 bits.
template <int SHIFT>
__device__ __forceinline__ void scan_pass(
    uint32_t* hist, bool rezero,
    uint32_t& prefA, uint32_t& remA, uint32_t& prefB, uint32_t& remB,
    uint32_t* wsum, volatile uint32_t* sh_scal, int tid, int lane, int wv) {
  __syncthreads();
  uint2 av = ((uint2*)hist)[tid];               // bins 2tid, 2tid+1 (packed)
  if (rezero) ((uint2*)hist)[tid] = make_uint2(0u, 0u);
  uint32_t P = av.x + av.y;                     // packed pair total
  uint32_t ia = P;
#pragma unroll
  for (int off = 1; off < 64; off <<= 1) {      // packed in-wave suffix scan
    uint32_t u = __shfl_down(ia, off);
    if (lane + off < 64) ia += u;
  }
  if (lane == 0) wsum[wv] = ia;
  __syncthreads();
  uint32_t t = wsum[lane & 15], o = t;
#pragma unroll
  for (int off = 1; off < 16; off <<= 1) {      // packed wave-total suffix
    uint32_t u = __shfl_down(t, off);
    if (lane + off < 16) t += u;
  }
  uint32_t e = (uint32_t)__builtin_amdgcn_readlane((int)(t - o), wv);
  uint32_t S = e + (ia - P);                    // packed strictly-after sum
  uint32_t SA = S & 0xFFFFu, SB = S >> 16;
  uint32_t a0A = av.x & 0xFFFFu, a0B = av.x >> 16;
  uint32_t a1A = av.y & 0xFFFFu, a1B = av.y >> 16;
  {
    uint32_t gt1 = SA, ge1 = a1A + SA, gt0 = ge1, ge0 = a0A + ge1;
    if (ge0 >= remA && gt0 < remA) { sh_scal[0] = prefA | ((uint32_t)(2 * tid) << SHIFT); sh_scal[1] = remA - gt0; }
    if (ge1 >= remA && gt1 < remA) { sh_scal[0] = prefA | ((uint32_t)(2 * tid + 1) << SHIFT); sh_scal[1] = remA - gt1; }
  }
  {
    uint32_t gt1 = SB, ge1 = a1B + SB, gt0 = ge1, ge0 = a0B + ge1;
    if (ge0 >= remB && gt0 < remB) { sh_scal[2] = prefB | ((uint32_t)(2 * tid) << SHIFT); sh_scal[3] = remB - gt0; }
    if (ge1 >= remB && gt1 < remB) { sh_scal[2] = prefB | ((uint32_t)(2 * tid + 1) << SHIFT); sh_scal[3] = remB - gt1; }
  }
  __syncthreads();
  prefA = sh_scal[0]; remA = sh_scal[1];
  prefB = sh_scal[2]; remB = sh_scal[3];
}

__global__ __launch_bounds__(THREADS, 8) void cdr_pair_kernel(
    const float* __restrict__ x_emb, const float* __restrict__ t_emb,
    const float* __restrict__ w75n, const float* __restrict__ wf,
    const int* __restrict__ pos_idx,
    float* __restrict__ row_loss, float* __restrict__ out_atomic,
    uint32_t fk0, uint32_t fk1) {
  __shared__ uint32_t hist[NBINS];      // 8 KB, packed A|B
  __shared__ uint32_t sel[2048];        // 8 KB (2032 used)
  __shared__ uint32_t candK[2][CMAX];   // 1 KB
  __shared__ uint16_t candC[2][CMAX];   // 0.5 KB
  __shared__ uint32_t wsum[16];
  __shared__ uint32_t sh_scal[4];
  __shared__ uint32_t sh_cnt[2], sh_tie[2], sh_nsel;
  __shared__ uint32_t sh_theta[2], sh_need[2];
  __shared__ int sh_pos[2 * P_POS];
  __shared__ float shA[16], shB[16], sh_pp[16];

  const int r0 = blockIdx.x;            // 0..2047
  const int r1 = r0 + HALF_B;
  const int tid = threadIdx.x;
  const int lane = tid & 63;
  const int wv = tid >> 6;

  ((uint2*)hist)[tid] = make_uint2(0u, 0u);
  if (tid < P_POS) sh_pos[tid] = pos_idx[r0 * P_POS + tid];
  else if (tid < 2 * P_POS) sh_pos[tid] = pos_idx[r1 * P_POS + (tid - P_POS)];
  if (tid == 0) sh_nsel = 0u;
  if (tid < 2) { sh_cnt[tid] = 0u; sh_tie[tid] = 0u; }
  __syncthreads();

  // consecutive-cols layout: this thread owns cols [tid*8, tid*8+8)
  const int colbase = tid * EPT;
  uint32_t m0 = 0u, m1 = 0u;
#pragma unroll
  for (int p = 0; p < P_POS; ++p) {
    int c0 = sh_pos[p], c1 = sh_pos[P_POS + p];
    if ((c0 >> 3) == tid) m0 |= 1u << (c0 & 7);
    if ((c1 >> 3) == tid) m1 |= 1u << (c1 & 7);
  }

  float wv8[EPT];
  if (w75n) {
    const float4* w4 = (const float4*)w75n;
    float4 wA = w4[2 * tid], wB = w4[2 * tid + 1];
    wv8[0] = wA.x; wv8[1] = wA.y; wv8[2] = wA.z; wv8[3] = wA.w;
    wv8[4] = wB.x; wv8[5] = wB.y; wv8[6] = wB.z; wv8[7] = wB.w;
  } else {
#pragma unroll
    for (int i = 0; i < EPT; ++i)
      wv8[i] = -hw_exp2(-0.75f * hw_log2(wf[colbase + i]));
  }

  // ---- phase 1: threefry -> keys (regs) with FUSED pass-1 histogram ----
  uint32_t k0[EPT], k1[EPT];
  const uint32_t H = 16777216u;   // (B*NT)/2
  const uint32_t nbase = (uint32_t)(r0 * NT_COLS + colbase);
#pragma unroll
  for (int i = 0; i < EPT; ++i) {
    uint32_t xa = nbase + (uint32_t)i, xb = xa + H;
    tf2x32(fk0, fk1, xa, xb);
    uint32_t ka = make_key(xa, wv8[i]);
    uint32_t kb = make_key(xb, wv8[i]);
    ka = ((m0 >> i) & 1u) ? 0u : ka;
    kb = ((m1 >> i) & 1u) ? 0u : kb;
    k0[i] = ka; k1[i] = kb;
    atomicAdd(&hist[ka >> 21], 1u);          // row A: low 16 bits
    atomicAdd(&hist[kb >> 21], 0x10000u);    // row B: high 16 bits
  }

  // ---- phase 2: digit 1 scan, then guarded digit 2 ----
  uint32_t prefA = 0u, prefB = 0u, remA = K_NEG, remB = K_NEG;
  scan_pass<21>(hist, true, prefA, remA, prefB, remB,
                wsum, sh_scal, tid, lane, wv);
  const uint32_t PM11 = 0xFFE00000u;
#pragma unroll
  for (int i = 0; i < EPT; ++i) {
    uint32_t ka = k0[i];
    if ((ka & PM11) == prefA) atomicAdd(&hist[(ka >> 10) & 0x7FFu], 1u);
    uint32_t kb = k1[i];
    if ((kb & PM11) == prefB) atomicAdd(&hist[(kb >> 10) & 0x7FFu], 0x10000u);
  }
  scan_pass<10>(hist, false, prefA, remA, prefB, remB,
                wsum, sh_scal, tid, lane, wv);
  const uint32_t PM22 = 0xFFFFFC00u;

  // ---- phase 3a: one sweep: compact definite-selected; collect candidates ----
#pragma unroll
  for (int i = 0; i < EPT; ++i) {
    const int col = colbase + i;
#pragma unroll
    for (int rsb = 0; rsb < 2; ++rsb) {
      uint32_t k = rsb ? k1[i] : k0[i];
      uint32_t pref = rsb ? prefB : prefA;
      uint32_t p22 = k & PM22;
      bool def = p22 > pref;
      uint64_t mb = __ballot(def);
      uint32_t base = 0u;
      if (lane == 0) base = atomicAdd(&sh_nsel, (uint32_t)__popcll(mb));
      base = (uint32_t)__builtin_amdgcn_readfirstlane((int)base);
      if (def) sel[base + mbcnt64(mb)] = (uint32_t)col | ((uint32_t)rsb << 13);
      if (p22 == pref) {
        uint32_t s = atomicAdd(&sh_cnt[rsb], 1u);
        if (s < CMAX) { candK[rsb][s] = k; candC[rsb][s] = (uint16_t)col; }
      }
    }
  }
  __syncthreads();

  // ---- phase 3b: resolve exact theta among the prefix-tied candidates ----
  if (tid < 2) {
    uint32_t c = sh_cnt[tid]; if (c > CMAX) c = CMAX;
    uint32_t rr = tid ? remB : remA;
    uint32_t th = 0u, nd = 0u;
    for (uint32_t j = 0; j < c; ++j) {
      uint32_t kj = candK[tid][j];
      uint32_t gt = 0u, eq = 0u;
      for (uint32_t l = 0; l < c; ++l) { gt += (candK[tid][l] > kj); eq += (candK[tid][l] == kj); }
      if (gt < rr && gt + eq >= rr) { th = kj; nd = rr - gt; }
    }
    sh_theta[tid] = th; sh_need[tid] = nd;
  }
  __syncthreads();

  // ---- phase 3c: append boundary candidates ----
  if (tid < 2 * CMAX) {
    const int rsb = tid >> 7;
    const uint32_t j = tid & (CMAX - 1);
    uint32_t c = sh_cnt[rsb]; if (c > CMAX) c = CMAX;
    if (j < c) {
      uint32_t k = candK[rsb][j];
      uint32_t th = sh_theta[rsb];
      bool inc = (k > th);
      if (k == th) inc = (atomicAdd(&sh_tie[rsb], 1u) < sh_need[rsb]);
      if (inc) {
        uint32_t s = atomicAdd(&sh_nsel, 1u);
        sel[s] = (uint32_t)candC[rsb][j] | ((uint32_t)rsb << 13);
      }
    }
  }
  __syncthreads();
  const uint32_t total = sh_nsel;   // == 2 * K_NEG

  const float xa0 = x_emb[r0 * 2], xa1 = x_emb[r0 * 2 + 1];
  const float xb0 = x_emb[r1 * 2], xb1 = x_emb[r1 * 2 + 1];
  const float qa = xa0 * xa0 + xa1 * xa1;
  const float qb = xb0 * xb0 + xb1 * xb1;
  const float2* temb2 = (const float2*)t_emb;

  // ---- phase 4: dense sweep over the 2032 selected entries ----
  float accA = 0.0f, accB = 0.0f;
  for (uint32_t j = tid; j < total; j += THREADS) {
    uint32_t e = sel[j];
    int col = e & 0x1FFFu;
    bool isB = (e & 0x2000u) != 0u;
    float2 t = temb2[col];
    float px = isB ? xb0 : xa0;
    float py = isB ? xb1 : xa1;
    float pq = isB ? qb : qa;
    float s = sim_fast(px, py, pq, t.x, t.y);
    float ez = hw_exp2(s * (INV_T * INV_LN2_F));
    if (isB) accB += ez; else accA += ez;
  }
#pragma unroll
  for (int off = 32; off > 0; off >>= 1) {
    accA += __shfl_down(accA, off);
    accB += __shfl_down(accB, off);
  }
  if (lane == 0) { shA[wv] = accA; shB[wv] = accB; }
  if (tid < 16) {
    int rowb = tid >> 3;
    int c = sh_pos[tid];
    float2 t = temb2[c];
    float px = rowb ? xb0 : xa0;
    float py = rowb ? xb1 : xa1;
    float pq = rowb ? qb : qa;
    sh_pp[tid] = sim_fast(px, py, pq, t.x, t.y);
  }
  __syncthreads();

  if (tid < 2) {
    float s = 0.0f;
#pragma unroll
    for (int w = 0; w < 16; ++w) s += tid ? shB[w] : shA[w];
    float ps = 0.0f;
#pragma unroll
    for (int p = 0; p < P_POS; ++p) ps += sh_pp[tid * P_POS + p];
    float pos = ps * (1.0f / P_POS);
    float zpos = pos * INV_T;
    float S = s + hw_exp2(zpos * INV_LN2_F) + N_PAD;
    float loss = logf(S) - zpos;
    int r = tid ? r1 : r0;
    if (row_loss) row_loss[r] = loss;
    else atomicAdd(out_atomic, loss * (1.0f / B_ROWS));
  }
}

__global__ __launch_bounds__(256) void cdr_reduce_kernel(
    const float* __restrict__ row_loss, float* __restrict__ out) {
  __shared__ float part[4];
  float s = 0.0f;
  for (int i = threadIdx.x; i < B_ROWS; i += 256) s += row_loss[i];
#pragma unroll
  for (int off = 32; off > 0; off >>= 1) s += __shfl_down(s, off);
  if ((threadIdx.x & 63) == 0) part[threadIdx.x >> 6] = s;
  __syncthreads();
  if (threadIdx.x == 0)
    out[0] = (part[0] + part[1] + part[2] + part[3]) * (1.0f / B_ROWS);
}

__global__ void cdr_zero_kernel(float* __restrict__ out) { out[0] = 0.0f; }

extern "C" void kernel_launch(void* const* d_in, const int* in_sizes, int n_in,
                              void* d_out, int out_size, void* d_ws, size_t ws_size,
                              hipStream_t stream) {
  const float* x_emb = (const float*)d_in[0];
  const float* t_emb = (const float*)d_in[1];
  const float* wf    = (const float*)d_in[2];
  const int*   pidx  = (const int*)d_in[3];
  float* out = (float*)d_out;

  uint32_t fk0 = 0u, fk1 = 1u;
  tf2x32(0u, 0u, fk0, fk1);

  const bool has_w75 = (ws_size >= (size_t)(NT_COLS + B_ROWS) * sizeof(float));
  const bool has_rl  = (ws_size >= (size_t)B_ROWS * sizeof(float));

  float* w75n = nullptr;
  float* row_loss = nullptr;
  if (has_w75) { w75n = (float*)d_ws; row_loss = (float*)d_ws + NT_COLS; }
  else if (has_rl) { row_loss = (float*)d_ws; }

  if (has_w75) {
    hipLaunchKernelGGL(prew_kernel, dim3(NT_COLS / 256), dim3(256), 0, stream,
                       wf, w75n);
  }
  if (!row_loss) {
    hipLaunchKernelGGL(cdr_zero_kernel, dim3(1), dim3(1), 0, stream, out);
  }
  hipLaunchKernelGGL(cdr_pair_kernel, dim3(HALF_B), dim3(THREADS), 0, stream,
                     x_emb, t_emb, w75n, wf, pidx, row_loss, out, fk0, fk1);
  if (row_loss) {
    hipLaunchKernelGGL(cdr_reduce_kernel, dim3(1), dim3(256), 0, stream,
                       row_loss, out);
  }
}